// Round 2
// baseline (186.646 us; speedup 1.0000x reference)
//
#include <hip/hip_runtime.h>
#include <hip/hip_bf16.h>
#include <stdint.h>

// Problem constants
#define NUM_C 1000
#define NB    4096
#define NO    4096
#define NCOL  9192          // NB + NUM_C + NO
#define NPAD  9216          // 72 * 128
#define DK    512
#define BM    128
#define BN    128
#define BK    32
#define INV_T 10.0f

typedef __attribute__((ext_vector_type(8))) short short8;
typedef __attribute__((ext_vector_type(4))) float f32x4;

// workspace layout (bytes)
#define OFF_FALL 0u                  // bf16 [NPAD][DK] = 9,437,184 B
#define OFF_CNT  9437184u            // uint[1024] histogram targets+pseudo
#define OFF_CNTT 9441280u            // uint[1024] histogram targets only
#define OFF_S    9445376u            // float[4096] S accumulators
#define OFF_P    9461760u            // float[4096] P accumulators
#define OFF_LBL  9478144u            // int[NPAD] targets_all label per column
#define OFF_RW   9515008u            // float2[NPAD] {1/w, 1/(w-1)} per column
#define ZERO_BYTES 40960u            // cnt+cntT+S+P contiguous

__device__ __forceinline__ void async16(const void* g, void* l) {
#if __has_builtin(__builtin_amdgcn_global_load_lds)
  __builtin_amdgcn_global_load_lds((const __attribute__((address_space(1))) void*)g,
                                   (__attribute__((address_space(3))) void*)l,
                                   16, 0, 0);
#else
  *(uint4*)l = *(const uint4*)g;
#endif
}

__device__ __forceinline__ ushort f2bf_rne(float f) {
  uint32_t u = __builtin_bit_cast(uint32_t, f);
  u += 0x7FFFu + ((u >> 16) & 1u);   // round to nearest even
  return (ushort)(u >> 16);
}

// Build features_all (bf16) = [features; centers1; features_ood; zeros-pad], f32 -> bf16
__global__ __launch_bounds__(256) void concat_k(const float* __restrict__ centers,
                                                const float* __restrict__ feats,
                                                const float* __restrict__ ood,
                                                ushort* __restrict__ fall) {
  int idx = blockIdx.x * 256 + threadIdx.x;   // one 8-elem chunk each; 9216*64 total
  int row = idx >> 6;
  int ck  = (idx & 63) * 8;
  ushort h[8];
  const float* src = nullptr;
  if (row < NB)              src = feats   + (size_t)row * DK + ck;
  else if (row < NB + NUM_C) src = centers + (size_t)(row - NB) * DK + ck;
  else if (row < NCOL)       src = ood     + (size_t)(row - NB - NUM_C) * DK + ck;
  if (src) {
    float4 v0 = *(const float4*)(src);
    float4 v1 = *(const float4*)(src + 4);
    h[0] = f2bf_rne(v0.x); h[1] = f2bf_rne(v0.y); h[2] = f2bf_rne(v0.z); h[3] = f2bf_rne(v0.w);
    h[4] = f2bf_rne(v1.x); h[5] = f2bf_rne(v1.y); h[6] = f2bf_rne(v1.z); h[7] = f2bf_rne(v1.w);
  } else {
    for (int i = 0; i < 8; i++) h[i] = 0;
  }
  *(uint4*)(fall + (size_t)row * DK + ck) = *(uint4*)h;
}

__global__ __launch_bounds__(256) void histo_k(const int* __restrict__ targets,
                                               const int* __restrict__ pseudo,
                                               unsigned* __restrict__ cnt,
                                               unsigned* __restrict__ cntT) {
  int i = blockIdx.x * 256 + threadIdx.x;
  if (i < NB) {
    int t = targets[i];
    atomicAdd(&cnt[t], 1u);
    atomicAdd(&cntT[t], 1u);
    atomicAdd(&cnt[pseudo[i]], 1u);
  }
}

// Per-column: label (targets_all) and reciprocal weights {1/w, 1/(w-1)}, w = cnt[tac]+1 (the center)
__global__ __launch_bounds__(256) void cols_k(const int* __restrict__ targets,
                                              const int* __restrict__ pseudo,
                                              const unsigned* __restrict__ cnt,
                                              int* __restrict__ lblAll,
                                              float2* __restrict__ rwAll) {
  int j = blockIdx.x * 256 + threadIdx.x;
  if (j >= NPAD) return;
  if (j >= NCOL) { lblAll[j] = -1; rwAll[j] = make_float2(0.f, 0.f); return; }
  int tac, lbl;
  if (j < NB)            { tac = targets[j]; lbl = tac; }
  else if (j < NB+NUM_C) { tac = j - NB;     lbl = tac; }
  else                   { tac = pseudo[j - NB - NUM_C]; lbl = NUM_C; }
  float w = (float)(cnt[tac] + 1u);
  lblAll[j] = lbl;
  rwAll[j] = make_float2(1.0f / w, 1.0f / (w - 1.0f)); // (w-1) slot only selected when a positive exists => w>=2
}

// Fused GEMM (bf16 MFMA) + per-row S/P partial reduction
__global__ __launch_bounds__(256) void gemm_fused(const ushort* __restrict__ fall,
                                                  const int* __restrict__ lblAll,
                                                  const float2* __restrict__ rwAll,
                                                  const int* __restrict__ targets,
                                                  float* __restrict__ Sacc,
                                                  float* __restrict__ Pacc) {
  __shared__ ushort As[BM * BK];   // [128][32] bf16, 8 KB
  __shared__ ushort Bs[BN * BK];   // 8 KB
  __shared__ int   sLbl[BN];
  __shared__ float sRw0[BN];
  __shared__ float sRw1[BN];
  __shared__ int   sTgt[BM];

  const int tid   = threadIdx.x;
  const int nTile = blockIdx.x;   // 72
  const int mTile = blockIdx.y;   // 32
  const int lane  = tid & 63;
  const int wv    = tid >> 6;     // wave 0..3
  const int wm    = wv >> 1;      // 0..1 row half
  const int wn    = wv & 1;       // 0..1 col half
  const int q     = lane >> 4;    // quad
  const int cIdx  = lane & 15;

  if (tid < BN) {
    int j = nTile * BN + tid;
    sLbl[tid] = lblAll[j];
    float2 rw = rwAll[j];
    sRw0[tid] = rw.x;
    sRw1[tid] = rw.y;
  } else {
    sTgt[tid - 128] = targets[mTile * BM + tid - 128];
  }

  f32x4 acc[4][4];
  for (int mi = 0; mi < 4; mi++)
    for (int ni = 0; ni < 4; ni++)
      acc[mi][ni] = (f32x4){0.f, 0.f, 0.f, 0.f};

  const int aRow0 = mTile * BM;   // rows are features (always < NB)
  const int bRow0 = nTile * BN;
  const int sRow  = tid >> 2;        // 0..63
  const int sKo   = (tid & 3) * 8;   // bf16 elems within the 32-wide k slab

  for (int kt = 0; kt < DK; kt += BK) {
    __syncthreads();
    async16(fall + (size_t)(aRow0 + sRow)      * DK + kt + sKo, &As[sRow * BK + sKo]);
    async16(fall + (size_t)(aRow0 + 64 + sRow) * DK + kt + sKo, &As[(64 + sRow) * BK + sKo]);
    async16(fall + (size_t)(bRow0 + sRow)      * DK + kt + sKo, &Bs[sRow * BK + sKo]);
    async16(fall + (size_t)(bRow0 + 64 + sRow) * DK + kt + sKo, &Bs[(64 + sRow) * BK + sKo]);
    __syncthreads();

    short8 af[4], bfr[4];
    for (int mi = 0; mi < 4; mi++)
      af[mi] = *(const short8*)&As[(wm * 64 + mi * 16 + cIdx) * BK + q * 8];
    for (int ni = 0; ni < 4; ni++)
      bfr[ni] = *(const short8*)&Bs[(wn * 64 + ni * 16 + cIdx) * BK + q * 8];
    for (int mi = 0; mi < 4; mi++)
      for (int ni = 0; ni < 4; ni++)
        acc[mi][ni] = __builtin_amdgcn_mfma_f32_16x16x32_bf16(af[mi], bfr[ni], acc[mi][ni], 0, 0, 0);
  }

  // Epilogue: l = acc*10; e = exp(l-10) * (diag?0 : pos?1/(w-1) : 1/w); P += pos?l:0
  float Sr[16], Pr[16];
  for (int s = 0; s < 16; s++) { Sr[s] = 0.f; Pr[s] = 0.f; }

  for (int ni = 0; ni < 4; ni++) {
    int jloc = wn * 64 + ni * 16 + cIdx;
    int j    = nTile * BN + jloc;
    int lblj = sLbl[jloc];
    float rw0 = sRw0[jloc], rw1 = sRw1[jloc];
    for (int mi = 0; mi < 4; mi++) {
      f32x4 a = acc[mi][ni];
      for (int r = 0; r < 4; r++) {
        int iloc = wm * 64 + mi * 16 + q * 4 + r;
        int i    = mTile * BM + iloc;
        int ti   = sTgt[iloc];
        float l  = a[r] * INV_T;
        bool diag = (j == i);
        bool pos  = (lblj == ti) && !diag;
        float rw  = diag ? 0.0f : (pos ? rw1 : rw0);
        float e   = __expf(l - 10.0f) * rw;
        Sr[mi * 4 + r] += e;
        Pr[mi * 4 + r] += pos ? l : 0.0f;
      }
    }
  }

  // reduce across the 16 col-lanes of each quad, then one atomic per row
  for (int s = 0; s < 16; s++) {
    float v = Sr[s], p = Pr[s];
    for (int m = 1; m < 16; m <<= 1) {
      v += __shfl_xor(v, m, 64);
      p += __shfl_xor(p, m, 64);
    }
    if (cIdx == 0) {
      int iloc = wm * 64 + (s >> 2) * 16 + q * 4 + (s & 3);
      int i    = mTile * BM + iloc;
      atomicAdd(&Sacc[i], v);
      atomicAdd(&Pacc[i], p);
    }
  }
}

// loss = -mean( P/npos - 10 - log S );  npos_i = cntT[targets[i]]
__global__ __launch_bounds__(256) void finalize_k(const float* __restrict__ S,
                                                  const float* __restrict__ P,
                                                  const int* __restrict__ targets,
                                                  const unsigned* __restrict__ cntT,
                                                  float* __restrict__ out) {
  __shared__ float red[4];
  int tid = threadIdx.x;
  float local = 0.f;
  for (int i = tid; i < NB; i += 256) {
    float npos = (float)cntT[targets[i]];
    local += P[i] / npos - INV_T - __logf(S[i]);
  }
  for (int m = 1; m < 64; m <<= 1) local += __shfl_xor(local, m, 64);
  if ((tid & 63) == 0) red[tid >> 6] = local;
  __syncthreads();
  if (tid == 0) {
    float t = red[0] + red[1] + red[2] + red[3];
    out[0] = -t / (float)NB;
  }
}

extern "C" void kernel_launch(void* const* d_in, const int* in_sizes, int n_in,
                              void* d_out, int out_size, void* d_ws, size_t ws_size,
                              hipStream_t stream) {
  const float* centers = (const float*)d_in[0];   // [1000][512] f32
  const float* feats   = (const float*)d_in[1];   // [4096][512] f32
  const int*   targets = (const int*)d_in[2];     // [4096] i32
  const float* ood     = (const float*)d_in[3];   // [4096][512] f32
  const int*   pseudo  = (const int*)d_in[4];     // [4096] i32

  char* ws = (char*)d_ws;
  ushort*   fall   = (ushort*)(ws + OFF_FALL);
  unsigned* cnt    = (unsigned*)(ws + OFF_CNT);
  unsigned* cntT   = (unsigned*)(ws + OFF_CNTT);
  float*    Sacc   = (float*)(ws + OFF_S);
  float*    Pacc   = (float*)(ws + OFF_P);
  int*      lblAll = (int*)(ws + OFF_LBL);
  float2*   rwAll  = (float2*)(ws + OFF_RW);

  hipMemsetAsync(ws + OFF_CNT, 0, ZERO_BYTES, stream);
  concat_k<<<dim3((NPAD * (DK / 8)) / 256), 256, 0, stream>>>(centers, feats, ood, fall);
  histo_k<<<dim3(NB / 256), 256, 0, stream>>>(targets, pseudo, cnt, cntT);
  cols_k<<<dim3(NPAD / 256), 256, 0, stream>>>(targets, pseudo, cnt, lblAll, rwAll);
  gemm_fused<<<dim3(NPAD / BN, NB / BM), 256, 0, stream>>>(fall, lblAll, rwAll, targets, Sacc, Pacc);
  finalize_k<<<1, 256, 0, stream>>>(Sacc, Pacc, targets, cntT, (float*)d_out);
}